// Round 12
// baseline (35.652 us; speedup 1.0000x reference)
//
#include <hip/hip_runtime.h>
#include <hip/hip_bf16.h>
#include <math.h>

// Problem constants (match reference)
#define V1N   225
#define V2N   224
#define RANK  64
#define ROWE  (RANK*32)   // 2048 elements per table row

typedef __bf16  bf16x8 __attribute__((ext_vector_type(8)));
typedef float  f32x16 __attribute__((ext_vector_type(16)));
typedef float  f32x4  __attribute__((ext_vector_type(4)));
typedef int    i32x4  __attribute__((ext_vector_type(4)));

// ---------------------------------------------------------------------------
// Prep: dequantize int8 cores into bf16 tables in d_ws (R6 version).
// Dst layout per row v: [s(4)][d(32)][rr(16)], r = s*16 + rr.
// ---------------------------------------------------------------------------
__global__ __launch_bounds__(256) void prep_tables(
    const int* __restrict__ c1q, const int* __restrict__ c2q,
    const float* __restrict__ s1p, const float* __restrict__ z1p,
    const float* __restrict__ s2p, const float* __restrict__ z2p,
    const float* __restrict__ phase,
    __bf16* __restrict__ t1, __bf16* __restrict__ t2)
{
    __shared__ float lds[64 * 33];
    __shared__ float cosv[RANK];

    int v = blockIdx.x;
    bool is1 = (v < V1N);
    const int* src;
    __bf16* dst;
    float sc, zp;
    if (is1) { src = c1q + v * ROWE;            dst = t1 + (size_t)v * ROWE;  sc = *s1p; zp = *z1p; }
    else     { int u = v - V1N; src = c2q + u * ROWE; dst = t2 + (size_t)u * ROWE; sc = *s2p; zp = *z2p; }

    int t = threadIdx.x;
    if (is1 && t < RANK) cosv[t] = cosf(phase[t]);
    __syncthreads();

    i32x4 w0 = reinterpret_cast<const i32x4*>(src)[t * 2];
    i32x4 w1 = reinterpret_cast<const i32x4*>(src)[t * 2 + 1];
    #pragma unroll
    for (int j = 0; j < 8; ++j) {
        int e = t * 8 + j;                 // src layout [r(64)][d(32)]
        int q = (j < 4) ? w0[j & 3] : w1[j & 3];
        float val = ((float)q - zp) * sc;
        if (is1) val *= cosv[e >> 5];
        lds[(e >> 5) * 33 + (e & 31)] = val;
    }
    __syncthreads();

    int s   = t >> 6;
    int d   = (t >> 1) & 31;
    int rr0 = (t & 1) * 8;
    bf16x8 o8;
    #pragma unroll
    for (int j = 0; j < 8; ++j) {
        int r = s * 16 + rr0 + j;
        o8[j] = (__bf16)lds[r * 33 + d];
    }
    *reinterpret_cast<bf16x8*>(dst + t * 8) = o8;
}

// ---------------------------------------------------------------------------
// Main: R6 version (best known, 22.5us total). One wave per token,
// swapped operands (A=c2, B=c1), wave-local stride-36 LDS transpose,
// dense nontemporal epilogue stores.
// ---------------------------------------------------------------------------
__global__ __launch_bounds__(256) void tt_main(
    const int* __restrict__ ids,
    const __bf16* __restrict__ t1, const __bf16* __restrict__ t2,
    float* __restrict__ out, int n_tok)
{
    __shared__ float tile[4][32 * 36];

    int w    = threadIdx.x >> 6;
    int wave = (blockIdx.x << 2) + w;
    if (wave >= n_tok) return;
    int lane = threadIdx.x & 63;
    int m = lane & 31;
    int g = lane >> 5;

    unsigned id = (unsigned)ids[wave];
    unsigned i1 = id / 224u; if (i1 > (unsigned)(V1N - 1)) i1 = V1N - 1;
    unsigned i2 = id % 224u;

    const __bf16* a_base = t2 + (size_t)i2 * ROWE + m * 16 + g * 8;  // A = c2
    const __bf16* b_base = t1 + (size_t)i1 * ROWE + m * 16 + g * 8;  // B = c1

    f32x16 acc;
    #pragma unroll
    for (int i = 0; i < 16; ++i) acc[i] = 0.0f;

    #pragma unroll
    for (int s = 0; s < 4; ++s) {
        bf16x8 a = *reinterpret_cast<const bf16x8*>(a_base + s * 512);
        bf16x8 b = *reinterpret_cast<const bf16x8*>(b_base + s * 512);
        acc = __builtin_amdgcn_mfma_f32_32x32x16_bf16(a, b, acc, 0, 0, 0);
    }

    float* tp = tile[w];
    #pragma unroll
    for (int q = 0; q < 4; ++q) {
        f32x4 v = { acc[4 * q + 0], acc[4 * q + 1], acc[4 * q + 2], acc[4 * q + 3] };
        *reinterpret_cast<f32x4*>(tp + m * 36 + 8 * q + 4 * g) = v;
    }

    float* o = out + (size_t)wave * 1024;
    #pragma unroll
    for (int p = 0; p < 4; ++p) {
        int d1 = p * 8 + (lane >> 3);
        int d2 = (lane & 7) * 4;
        f32x4 v = *reinterpret_cast<const f32x4*>(tp + d1 * 36 + d2);
        __builtin_nontemporal_store(v, reinterpret_cast<f32x4*>(o + p * 256 + lane * 4));
    }
}

// ---------------------------------------------------------------------------
// DIAGNOSTIC PROBE (read+store): exact replica of tt_main's memory traffic
// -- id load, all 8 fragment loads (live via asm sinks), 4 dense nt stores
// -- but NO MFMA/LDS. Isolates whether read traffic and write traffic
// share a throughput-limited vmem path:
//   delta ~= 11-13us -> reads ride free (port-sharing theory dead)
//   delta ~= 16-20us -> shared-port confirmed -> read-halving is the fix
// Runs after tt_main; prep rebuilds tables each call, so clobbering ws is
// deterministic-safe (R7-verified pattern). Garbage reads are value-sunk.
// ---------------------------------------------------------------------------
__global__ __launch_bounds__(256) void probe_rw(
    const int* __restrict__ ids,
    const __bf16* __restrict__ t1, const __bf16* __restrict__ t2,
    float* __restrict__ ws, int n_tok)
{
    int w    = threadIdx.x >> 6;
    int wave = (blockIdx.x << 2) + w;
    if (wave >= n_tok) return;
    int lane = threadIdx.x & 63;
    int m = lane & 31;
    int g = lane >> 5;

    unsigned id = (unsigned)ids[wave];
    unsigned i1 = id / 224u; if (i1 > (unsigned)(V1N - 1)) i1 = V1N - 1;
    unsigned i2 = id % 224u;

    const __bf16* a_base = t2 + (size_t)i2 * ROWE + m * 16 + g * 8;
    const __bf16* b_base = t1 + (size_t)i1 * ROWE + m * 16 + g * 8;

    #pragma unroll
    for (int s = 0; s < 4; ++s) {
        bf16x8 a = *reinterpret_cast<const bf16x8*>(a_base + s * 512);
        bf16x8 b = *reinterpret_cast<const bf16x8*>(b_base + s * 512);
        asm volatile("" :: "v"(a), "v"(b));   // keep loads live (rule #17)
    }

    float* o = ws + (size_t)wave * 1024;
    f32x4 v = { 1.0f, 2.0f, 3.0f, 4.0f };
    #pragma unroll
    for (int p = 0; p < 4; ++p) {
        __builtin_nontemporal_store(v, reinterpret_cast<f32x4*>(o + p * 256 + lane * 4));
    }
}

// ---------------------------------------------------------------------------
// Fallback (if d_ws is too small): fused on-the-fly dequant + MFMA.
// ---------------------------------------------------------------------------
__global__ __launch_bounds__(256) void tt_fused(
    const int* __restrict__ ids,
    const int* __restrict__ c1q, const int* __restrict__ c2q,
    const float* __restrict__ s1p, const float* __restrict__ z1p,
    const float* __restrict__ s2p, const float* __restrict__ z2p,
    const float* __restrict__ phase,
    float* __restrict__ out, int n_tok)
{
    __shared__ float cosv[RANK];
    if (threadIdx.x < RANK) cosv[threadIdx.x] = cosf(phase[threadIdx.x]);
    __syncthreads();

    int wave = (blockIdx.x << 2) + (threadIdx.x >> 6);
    if (wave >= n_tok) return;
    int lane = threadIdx.x & 63;
    int m = lane & 31;
    int g = lane >> 5;

    float s1 = *s1p, z1 = *z1p, s2 = *s2p, z2 = *z2p;

    unsigned id = (unsigned)ids[wave];
    unsigned i1 = id / 224u; if (i1 > (unsigned)(V1N - 1)) i1 = V1N - 1;
    unsigned i2 = id % 224u;

    const int* a_src = c2q + (size_t)i2 * ROWE + m;   // A = c2, [r][d] stride 32
    const int* b_src = c1q + (size_t)i1 * ROWE + m;   // B = c1

    f32x16 acc;
    #pragma unroll
    for (int i = 0; i < 16; ++i) acc[i] = 0.0f;

    #pragma unroll
    for (int s = 0; s < 4; ++s) {
        bf16x8 a, b;
        #pragma unroll
        for (int j = 0; j < 8; ++j) {
            int r = s * 16 + g * 8 + j;
            a[j] = (__bf16)((((float)a_src[r * 32]) - z2) * s2);
            b[j] = (__bf16)((((float)b_src[r * 32]) - z1) * s1 * cosv[r]);
        }
        acc = __builtin_amdgcn_mfma_f32_32x32x16_bf16(a, b, acc, 0, 0, 0);
    }

    float* o = out + (size_t)wave * 1024 + m * 32 + g * 4;
    #pragma unroll
    for (int q = 0; q < 4; ++q) {
        f32x4 v = { acc[4 * q + 0], acc[4 * q + 1], acc[4 * q + 2], acc[4 * q + 3] };
        __builtin_nontemporal_store(v, reinterpret_cast<f32x4*>(o + 8 * q));
    }
}

extern "C" void kernel_launch(void* const* d_in, const int* in_sizes, int n_in,
                              void* d_out, int out_size, void* d_ws, size_t ws_size,
                              hipStream_t stream) {
    const int*   ids = (const int*)d_in[0];
    const int*   c1q = (const int*)d_in[1];   // int8 values delivered as int32
    const float* s1  = (const float*)d_in[2];
    const float* z1  = (const float*)d_in[3];
    const int*   c2q = (const int*)d_in[4];
    const float* s2  = (const float*)d_in[5];
    const float* z2  = (const float*)d_in[6];
    const float* ph  = (const float*)d_in[7];
    float* out = (float*)d_out;

    int n_tok = in_sizes[0];                  // 16384
    int grid  = (n_tok + 3) / 4;              // 4 waves (tokens) per block

    size_t need = (size_t)(V1N + V2N) * ROWE * sizeof(__bf16);  // ~1.84 MB
    if (ws_size >= need) {
        __bf16* t1 = (__bf16*)d_ws;
        __bf16* t2 = t1 + (size_t)V1N * ROWE;
        prep_tables<<<V1N + V2N, 256, 0, stream>>>(c1q, c2q, s1, z1, s2, z2, ph, t1, t2);
        tt_main<<<grid, 256, 0, stream>>>(ids, t1, t2, out, n_tok);

        // diagnostic: read+store replica of tt_main's traffic into ws
        int n_probe = (int)((ws_size / (1024 * sizeof(float)) < (size_t)n_tok)
                            ? ws_size / (1024 * sizeof(float)) : (size_t)n_tok);
        if (n_probe > 0) {
            int pgrid = (n_probe + 3) / 4;
            probe_rw<<<pgrid, 256, 0, stream>>>(ids, t1, t2, (float*)d_ws, n_probe);
        }
    } else {
        int fgrid = (n_tok + 3) / 4;
        tt_fused<<<fgrid, 256, 0, stream>>>(ids, c1q, c2q, s1, z1, s2, z2, ph, out, n_tok);
    }
}

// Round 13
// 22.537 us; speedup vs baseline: 1.5820x; 1.5820x over previous
//
#include <hip/hip_runtime.h>
#include <hip/hip_bf16.h>
#include <math.h>

// Problem constants (match reference)
#define V1N   225
#define V2N   224
#define RANK  64
#define ROWE  (RANK*32)   // 2048 elements per table row

typedef __bf16  bf16x8 __attribute__((ext_vector_type(8)));
typedef float  f32x16 __attribute__((ext_vector_type(16)));
typedef float  f32x4  __attribute__((ext_vector_type(4)));
typedef int    i32x4  __attribute__((ext_vector_type(4)));

// ---------------------------------------------------------------------------
// Prep: dequantize int8 cores into bf16 tables in d_ws (R6 version).
// Dst layout per row v: [s(4)][d(32)][rr(16)], r = s*16 + rr, so each MFMA
// fragment load in tt_main is one contiguous 16B.
// core1 gets scale*(q-zp)*cos(phase[r]); core2 gets scale*(q-zp).
// ---------------------------------------------------------------------------
__global__ __launch_bounds__(256) void prep_tables(
    const int* __restrict__ c1q, const int* __restrict__ c2q,
    const float* __restrict__ s1p, const float* __restrict__ z1p,
    const float* __restrict__ s2p, const float* __restrict__ z2p,
    const float* __restrict__ phase,
    __bf16* __restrict__ t1, __bf16* __restrict__ t2)
{
    __shared__ float lds[64 * 33];
    __shared__ float cosv[RANK];

    int v = blockIdx.x;
    bool is1 = (v < V1N);
    const int* src;
    __bf16* dst;
    float sc, zp;
    if (is1) { src = c1q + v * ROWE;            dst = t1 + (size_t)v * ROWE;  sc = *s1p; zp = *z1p; }
    else     { int u = v - V1N; src = c2q + u * ROWE; dst = t2 + (size_t)u * ROWE; sc = *s2p; zp = *z2p; }

    int t = threadIdx.x;
    if (is1 && t < RANK) cosv[t] = cosf(phase[t]);
    __syncthreads();

    i32x4 w0 = reinterpret_cast<const i32x4*>(src)[t * 2];
    i32x4 w1 = reinterpret_cast<const i32x4*>(src)[t * 2 + 1];
    #pragma unroll
    for (int j = 0; j < 8; ++j) {
        int e = t * 8 + j;                 // src layout [r(64)][d(32)]
        int q = (j < 4) ? w0[j & 3] : w1[j & 3];
        float val = ((float)q - zp) * sc;
        if (is1) val *= cosv[e >> 5];
        lds[(e >> 5) * 33 + (e & 31)] = val;
    }
    __syncthreads();

    int s   = t >> 6;
    int d   = (t >> 1) & 31;
    int rr0 = (t & 1) * 8;
    bf16x8 o8;
    #pragma unroll
    for (int j = 0; j < 8; ++j) {
        int r = s * 16 + rr0 + j;
        o8[j] = (__bf16)lds[r * 33 + d];
    }
    *reinterpret_cast<bf16x8*>(dst + t * 8) = o8;
}

// ---------------------------------------------------------------------------
// Main: R6 structure (best known) + PINNED FULL OCCUPANCY.
// __launch_bounds__(256, 8): 8 waves/EU -> compiler caps VGPR <= 64 ->
// 32 waves/CU. The R11 probe (tiny VGPR, no LDS, full occupancy) ran the
// SAME memory traffic in 13.1us; main's extra ~5-6us is compute failing to
// hide -- occupancy is the last unpinned variable between the two.
// One wave per token; swapped operands (A=c2, B=c1); wave-local stride-36
// LDS transpose (b128 both sides, no barrier); dense NONTEMPORAL epilogue
// (lane i -> tile_base + i*16B, 1KB per store instruction).
// C/D layout (HW-verified): col=lane&31, row=(reg&3)+8*(reg>>2)+4*(lane>>5).
// ---------------------------------------------------------------------------
__global__ __launch_bounds__(256, 8) void tt_main(
    const int* __restrict__ ids,
    const __bf16* __restrict__ t1, const __bf16* __restrict__ t2,
    float* __restrict__ out, int n_tok)
{
    __shared__ float tile[4][32 * 36];

    int w    = threadIdx.x >> 6;
    int wave = (blockIdx.x << 2) + w;
    if (wave >= n_tok) return;
    int lane = threadIdx.x & 63;
    int m = lane & 31;
    int g = lane >> 5;

    unsigned id = (unsigned)ids[wave];
    unsigned i1 = id / 224u; if (i1 > (unsigned)(V1N - 1)) i1 = V1N - 1;
    unsigned i2 = id % 224u;

    const __bf16* a_base = t2 + (size_t)i2 * ROWE + m * 16 + g * 8;  // A = c2
    const __bf16* b_base = t1 + (size_t)i1 * ROWE + m * 16 + g * 8;  // B = c1

    f32x16 acc;
    #pragma unroll
    for (int i = 0; i < 16; ++i) acc[i] = 0.0f;

    #pragma unroll
    for (int s = 0; s < 4; ++s) {
        bf16x8 a = *reinterpret_cast<const bf16x8*>(a_base + s * 512);
        bf16x8 b = *reinterpret_cast<const bf16x8*>(b_base + s * 512);
        acc = __builtin_amdgcn_mfma_f32_32x32x16_bf16(a, b, acc, 0, 0, 0);
    }

    // stage tile[d1][d2] = acc: d1 = m, d2 = 8*q + 4*g + j (16B-aligned b128)
    float* tp = tile[w];
    #pragma unroll
    for (int q = 0; q < 4; ++q) {
        f32x4 v = { acc[4 * q + 0], acc[4 * q + 1], acc[4 * q + 2], acc[4 * q + 3] };
        *reinterpret_cast<f32x4*>(tp + m * 36 + 8 * q + 4 * g) = v;
    }

    // dense epilogue: flat offset = p*256 + lane*4
    float* o = out + (size_t)wave * 1024;
    #pragma unroll
    for (int p = 0; p < 4; ++p) {
        int d1 = p * 8 + (lane >> 3);
        int d2 = (lane & 7) * 4;
        f32x4 v = *reinterpret_cast<const f32x4*>(tp + d1 * 36 + d2);
        __builtin_nontemporal_store(v, reinterpret_cast<f32x4*>(o + p * 256 + lane * 4));
    }
}

// ---------------------------------------------------------------------------
// Fallback (if d_ws is too small): fused on-the-fly dequant + MFMA.
// ---------------------------------------------------------------------------
__global__ __launch_bounds__(256) void tt_fused(
    const int* __restrict__ ids,
    const int* __restrict__ c1q, const int* __restrict__ c2q,
    const float* __restrict__ s1p, const float* __restrict__ z1p,
    const float* __restrict__ s2p, const float* __restrict__ z2p,
    const float* __restrict__ phase,
    float* __restrict__ out, int n_tok)
{
    __shared__ float cosv[RANK];
    if (threadIdx.x < RANK) cosv[threadIdx.x] = cosf(phase[threadIdx.x]);
    __syncthreads();

    int wave = (blockIdx.x << 2) + (threadIdx.x >> 6);
    if (wave >= n_tok) return;
    int lane = threadIdx.x & 63;
    int m = lane & 31;
    int g = lane >> 5;

    float s1 = *s1p, z1 = *z1p, s2 = *s2p, z2 = *z2p;

    unsigned id = (unsigned)ids[wave];
    unsigned i1 = id / 224u; if (i1 > (unsigned)(V1N - 1)) i1 = V1N - 1;
    unsigned i2 = id % 224u;

    const int* a_src = c2q + (size_t)i2 * ROWE + m;   // A = c2, [r][d] stride 32
    const int* b_src = c1q + (size_t)i1 * ROWE + m;   // B = c1

    f32x16 acc;
    #pragma unroll
    for (int i = 0; i < 16; ++i) acc[i] = 0.0f;

    #pragma unroll
    for (int s = 0; s < 4; ++s) {
        bf16x8 a, b;
        #pragma unroll
        for (int j = 0; j < 8; ++j) {
            int r = s * 16 + g * 8 + j;
            a[j] = (__bf16)((((float)a_src[r * 32]) - z2) * s2);
            b[j] = (__bf16)((((float)b_src[r * 32]) - z1) * s1 * cosv[r]);
        }
        acc = __builtin_amdgcn_mfma_f32_32x32x16_bf16(a, b, acc, 0, 0, 0);
    }

    float* o = out + (size_t)wave * 1024 + m * 32 + g * 4;
    #pragma unroll
    for (int q = 0; q < 4; ++q) {
        f32x4 v = { acc[4 * q + 0], acc[4 * q + 1], acc[4 * q + 2], acc[4 * q + 3] };
        __builtin_nontemporal_store(v, reinterpret_cast<f32x4*>(o + 8 * q));
    }
}

extern "C" void kernel_launch(void* const* d_in, const int* in_sizes, int n_in,
                              void* d_out, int out_size, void* d_ws, size_t ws_size,
                              hipStream_t stream) {
    const int*   ids = (const int*)d_in[0];
    const int*   c1q = (const int*)d_in[1];   // int8 values delivered as int32
    const float* s1  = (const float*)d_in[2];
    const float* z1  = (const float*)d_in[3];
    const int*   c2q = (const int*)d_in[4];
    const float* s2  = (const float*)d_in[5];
    const float* z2  = (const float*)d_in[6];
    const float* ph  = (const float*)d_in[7];
    float* out = (float*)d_out;

    int n_tok = in_sizes[0];                  // 16384
    int grid  = (n_tok + 3) / 4;              // 4 waves (tokens) per block

    size_t need = (size_t)(V1N + V2N) * ROWE * sizeof(__bf16);  // ~1.84 MB
    if (ws_size >= need) {
        __bf16* t1 = (__bf16*)d_ws;
        __bf16* t2 = t1 + (size_t)V1N * ROWE;
        prep_tables<<<V1N + V2N, 256, 0, stream>>>(c1q, c2q, s1, z1, s2, z2, ph, t1, t2);
        tt_main<<<grid, 256, 0, stream>>>(ids, t1, t2, out, n_tok);
    } else {
        int fgrid = (n_tok + 3) / 4;
        tt_fused<<<fgrid, 256, 0, stream>>>(ids, c1q, c2q, s1, z1, s2, z2, ph, out, n_tok);
    }
}